// Round 1
// baseline (3607.513 us; speedup 1.0000x reference)
//
#include <hip/hip_runtime.h>
#include <math.h>

// Problem constants
#define B 4
#define S 2048
#define D 512
#define H 8
#define HD 64
#define M_TOT (B * S)              // 8192 rows in the [B*S, D] view
#define X_SIZE (B * S * D)         // 4194304 floats, output x
#define STRIDE_BH (S * HD)         // 131072  ([B,H,S,HD] h-stride)
#define STRIDE_B (H * S * HD)      // 1048576 ([B,H,S,HD] b-stride)

// ---------------------------------------------------------------------------
// GEMM 1: projection.  out[b,h,s,hd] = sum_k X[m,k] * W[n,k] + bias[n]
// X: [M_TOT, D] row-major.  W: [D, D] row-major (torch Linear: x @ W^T).
// n = h*64 + hd, m = b*2048 + s.  Tile 64x64, BK=32, 256 thr, 4x4/thread.
// ---------------------------------------------------------------------------
__global__ __launch_bounds__(256) void gemm_proj(
    const float* __restrict__ X, const float* __restrict__ W,
    const float* __restrict__ bias, float* __restrict__ out) {
  __shared__ float As[64][33];
  __shared__ float Bs[64][33];
  const int tid = threadIdx.x;
  const int tx = tid & 15, ty = tid >> 4;
  const int n0 = blockIdx.x * 64;   // == h*64 (one head per n-tile)
  const int m0 = blockIdx.y * 64;
  float acc[4][4] = {};

  for (int k0 = 0; k0 < D; k0 += 32) {
#pragma unroll
    for (int i = 0; i < 8; ++i) {
      int l = tid + i * 256;
      int r = l >> 5, kk = l & 31;
      As[r][kk] = X[(size_t)(m0 + r) * D + (k0 + kk)];
      Bs[r][kk] = W[(size_t)(n0 + r) * D + (k0 + kk)];
    }
    __syncthreads();
#pragma unroll
    for (int kk = 0; kk < 32; ++kk) {
      float a[4], b[4];
#pragma unroll
      for (int i = 0; i < 4; ++i) a[i] = As[ty * 4 + i][kk];
#pragma unroll
      for (int j = 0; j < 4; ++j) b[j] = Bs[tx * 4 + j][kk];
#pragma unroll
      for (int i = 0; i < 4; ++i)
#pragma unroll
        for (int j = 0; j < 4; ++j) acc[i][j] += a[i] * b[j];
    }
    __syncthreads();
  }

  const int h = blockIdx.x;
#pragma unroll
  for (int i = 0; i < 4; ++i) {
    int m = m0 + ty * 4 + i;
    int b = m >> 11, s = m & 2047;
    float* orow = out + (size_t)b * STRIDE_B + (size_t)h * STRIDE_BH + (size_t)s * HD;
#pragma unroll
    for (int j = 0; j < 4; ++j) {
      int hd = tx * 4 + j;
      orow[hd] = acc[i][j] + bias[n0 + hd];
    }
  }
}

// ---------------------------------------------------------------------------
// Scores + mask + softmax.  One block = (b,h, 4 query rows).
// Keeps the 4x2048 score strip in LDS so dist is written to HBM exactly once.
// ---------------------------------------------------------------------------
__global__ __launch_bounds__(256) void attn_softmax(
    const float* __restrict__ q, const float* __restrict__ k,
    const int* __restrict__ mask, float* __restrict__ dist) {
  __shared__ float qs[4][64];
  __shared__ float sc[4][2048];
  __shared__ float red[4][4];

  const int tid = threadIdx.x;
  const int blk = blockIdx.x;          // 0..16383
  const int bh = blk >> 9;             // 512 row-blocks per (b,h)
  const int row0 = (blk & 511) * 4;
  const int b = bh >> 3;

  const float* qb = q + (size_t)bh * STRIDE_BH;
  const float* kb = k + (size_t)bh * STRIDE_BH;

  {  // load 4 q rows (256 floats, one per thread)
    int r = tid >> 6, c = tid & 63;
    qs[r][c] = qb[(size_t)(row0 + r) * HD + c];
  }
  __syncthreads();

  // scores: each thread handles 8 columns; one K-row read serves 4 q-rows
  for (int c8 = 0; c8 < 8; ++c8) {
    int col = c8 * 256 + tid;
    const float4* kp = (const float4*)(kb + (size_t)col * HD);
    float d0 = 0.f, d1 = 0.f, d2 = 0.f, d3 = 0.f;
#pragma unroll
    for (int i = 0; i < 16; ++i) {
      float4 kv = kp[i];
      d0 += kv.x * qs[0][4 * i] + kv.y * qs[0][4 * i + 1] + kv.z * qs[0][4 * i + 2] + kv.w * qs[0][4 * i + 3];
      d1 += kv.x * qs[1][4 * i] + kv.y * qs[1][4 * i + 1] + kv.z * qs[1][4 * i + 2] + kv.w * qs[1][4 * i + 3];
      d2 += kv.x * qs[2][4 * i] + kv.y * qs[2][4 * i + 1] + kv.z * qs[2][4 * i + 2] + kv.w * qs[2][4 * i + 3];
      d3 += kv.x * qs[3][4 * i] + kv.y * qs[3][4 * i + 1] + kv.z * qs[3][4 * i + 2] + kv.w * qs[3][4 * i + 3];
    }
    size_t mbase = (size_t)b * S * S + (size_t)row0 * S + col;  // mask [B,1,S,S]
    sc[0][col] = mask[mbase]          ? -1e10f : d0 * 0.125f;
    sc[1][col] = mask[mbase + S]      ? -1e10f : d1 * 0.125f;
    sc[2][col] = mask[mbase + 2 * S]  ? -1e10f : d2 * 0.125f;
    sc[3][col] = mask[mbase + 3 * S]  ? -1e10f : d3 * 0.125f;
  }
  __syncthreads();

  // row max
  float mx[4];
#pragma unroll
  for (int r = 0; r < 4; ++r) {
    float m = -INFINITY;
    for (int i = tid; i < S; i += 256) m = fmaxf(m, sc[r][i]);
#pragma unroll
    for (int off = 32; off > 0; off >>= 1) m = fmaxf(m, __shfl_down(m, off, 64));
    if ((tid & 63) == 0) red[r][tid >> 6] = m;
  }
  __syncthreads();
#pragma unroll
  for (int r = 0; r < 4; ++r)
    mx[r] = fmaxf(fmaxf(red[r][0], red[r][1]), fmaxf(red[r][2], red[r][3]));
  __syncthreads();  // everyone done reading red before it's rewritten

  // exp + row sum (exp written back in place)
  float sm[4];
#pragma unroll
  for (int r = 0; r < 4; ++r) {
    float s = 0.f;
    for (int i = tid; i < S; i += 256) {
      float e = __expf(sc[r][i] - mx[r]);
      sc[r][i] = e;
      s += e;
    }
#pragma unroll
    for (int off = 32; off > 0; off >>= 1) s += __shfl_down(s, off, 64);
    if ((tid & 63) == 0) red[r][tid >> 6] = s;
  }
  __syncthreads();
#pragma unroll
  for (int r = 0; r < 4; ++r) sm[r] = red[r][0] + red[r][1] + red[r][2] + red[r][3];

  // normalize + write dist
  size_t dbase = (size_t)bh * S * S + (size_t)row0 * S;
#pragma unroll
  for (int r = 0; r < 4; ++r) {
    float inv = 1.0f / sm[r];
    for (int i = tid; i < S; i += 256)
      dist[dbase + (size_t)r * S + i] = sc[r][i] * inv;
  }
}

// ---------------------------------------------------------------------------
// GEMM 2: attn = dist @ v.  Per (b,h): M=2048, N=64, K=2048.
// ---------------------------------------------------------------------------
__global__ __launch_bounds__(256) void gemm_av(
    const float* __restrict__ dist, const float* __restrict__ v,
    float* __restrict__ attn) {
  __shared__ float As[64][33];
  __shared__ float Bs[32][65];
  const int tid = threadIdx.x;
  const int tx = tid & 15, ty = tid >> 4;
  const int bh = blockIdx.y;
  const int m0 = blockIdx.x * 64;

  const float* Ab = dist + (size_t)bh * S * S;
  const float* Vb = v + (size_t)bh * STRIDE_BH;
  float acc[4][4] = {};

  for (int k0 = 0; k0 < S; k0 += 32) {
#pragma unroll
    for (int i = 0; i < 8; ++i) {
      int l = tid + i * 256;
      int r = l >> 5, kk = l & 31;
      As[r][kk] = Ab[(size_t)(m0 + r) * S + (k0 + kk)];
    }
#pragma unroll
    for (int i = 0; i < 8; ++i) {
      int l = tid + i * 256;
      int kk = l >> 6, n = l & 63;
      Bs[kk][n] = Vb[(size_t)(k0 + kk) * HD + n];
    }
    __syncthreads();
#pragma unroll
    for (int kk = 0; kk < 32; ++kk) {
      float a[4], bb[4];
#pragma unroll
      for (int i = 0; i < 4; ++i) a[i] = As[ty * 4 + i][kk];
#pragma unroll
      for (int j = 0; j < 4; ++j) bb[j] = Bs[kk][tx * 4 + j];
#pragma unroll
      for (int i = 0; i < 4; ++i)
#pragma unroll
        for (int j = 0; j < 4; ++j) acc[i][j] += a[i] * bb[j];
    }
    __syncthreads();
  }

  float* Ob = attn + (size_t)bh * STRIDE_BH;
#pragma unroll
  for (int i = 0; i < 4; ++i)
#pragma unroll
    for (int j = 0; j < 4; ++j)
      Ob[(size_t)(m0 + ty * 4 + i) * HD + (tx * 4 + j)] = acc[i][j];
}

// ---------------------------------------------------------------------------
// GEMM 3: x[m,n] = sum_k attn_flat[m,k] * Wo[n,k] + bo[n]
// attn_flat[m, k=h*64+hd] gathered from [B,H,S,HD] layout.
// ---------------------------------------------------------------------------
__global__ __launch_bounds__(256) void gemm_out(
    const float* __restrict__ attn, const float* __restrict__ W,
    const float* __restrict__ bias, float* __restrict__ out) {
  __shared__ float As[64][33];
  __shared__ float Bs[64][33];
  const int tid = threadIdx.x;
  const int tx = tid & 15, ty = tid >> 4;
  const int n0 = blockIdx.x * 64;
  const int m0 = blockIdx.y * 64;
  float acc[4][4] = {};

  for (int k0 = 0; k0 < D; k0 += 32) {
#pragma unroll
    for (int i = 0; i < 8; ++i) {
      int l = tid + i * 256;
      int r = l >> 5, kk = l & 31;
      int m = m0 + r, k = k0 + kk;
      int b = m >> 11, s = m & 2047, h = k >> 6, hd = k & 63;
      As[r][kk] = attn[(size_t)b * STRIDE_B + (size_t)h * STRIDE_BH + (size_t)s * HD + hd];
      Bs[r][kk] = W[(size_t)(n0 + r) * D + k];
    }
    __syncthreads();
#pragma unroll
    for (int kk = 0; kk < 32; ++kk) {
      float a[4], b[4];
#pragma unroll
      for (int i = 0; i < 4; ++i) a[i] = As[ty * 4 + i][kk];
#pragma unroll
      for (int j = 0; j < 4; ++j) b[j] = Bs[tx * 4 + j][kk];
#pragma unroll
      for (int i = 0; i < 4; ++i)
#pragma unroll
        for (int j = 0; j < 4; ++j) acc[i][j] += a[i] * b[j];
    }
    __syncthreads();
  }

#pragma unroll
  for (int i = 0; i < 4; ++i) {
    int m = m0 + ty * 4 + i;
#pragma unroll
    for (int j = 0; j < 4; ++j) {
      int n = n0 + tx * 4 + j;
      out[(size_t)m * D + n] = acc[i][j] + bias[n];
    }
  }
}

// ---------------------------------------------------------------------------
extern "C" void kernel_launch(void* const* d_in, const int* in_sizes, int n_in,
                              void* d_out, int out_size, void* d_ws, size_t ws_size,
                              hipStream_t stream) {
  const float* Q    = (const float*)d_in[0];
  const float* K    = (const float*)d_in[1];
  const float* V    = (const float*)d_in[2];
  const int*   mask = (const int*)d_in[3];   // bool -> int32 per harness convention
  const float* Wq   = (const float*)d_in[4];
  const float* bq   = (const float*)d_in[5];
  const float* Wk   = (const float*)d_in[6];
  const float* bk   = (const float*)d_in[7];
  const float* Wv   = (const float*)d_in[8];
  const float* bv   = (const float*)d_in[9];
  const float* Wo   = (const float*)d_in[10];
  const float* bo   = (const float*)d_in[11];

  float* x_out = (float*)d_out;              // [B,S,D]
  float* dist  = x_out + (size_t)X_SIZE;     // [B,H,S,S]

  float* ws   = (float*)d_ws;
  float* qb   = ws;                          // [B,H,S,HD]
  float* kb   = ws + (size_t)X_SIZE;
  float* vb   = ws + 2 * (size_t)X_SIZE;
  float* attn = ws + 3 * (size_t)X_SIZE;

  dim3 blk(256);
  dim3 gproj(D / 64, M_TOT / 64);            // (8, 128)

  gemm_proj<<<gproj, blk, 0, stream>>>(Q, Wq, bq, qb);
  gemm_proj<<<gproj, blk, 0, stream>>>(K, Wk, bk, kb);
  gemm_proj<<<gproj, blk, 0, stream>>>(V, Wv, bv, vb);
  attn_softmax<<<dim3(B * H * S / 4), blk, 0, stream>>>(qb, kb, mask, dist);
  gemm_av<<<dim3(S / 64, B * H), blk, 0, stream>>>(dist, vb, attn);
  gemm_out<<<gproj, blk, 0, stream>>>(attn, Wo, bo, x_out);
}

// Round 2
// 1487.373 us; speedup vs baseline: 2.4254x; 2.4254x over previous
//
#include <hip/hip_runtime.h>
#include <hip/hip_bf16.h>
#include <math.h>

// Problem constants
#define B 4
#define S 2048
#define D 512
#define H 8
#define HD 64
#define M_TOT (B * S)              // 8192 rows in the [B*S, D] view
#define X_SIZE (B * S * D)         // 4194304 elements
#define STRIDE_BH (S * HD)         // 131072  ([B,H,S,HD] h-stride)
#define STRIDE_B (H * S * HD)      // 1048576 ([B,H,S,HD] b-stride)

typedef __attribute__((ext_vector_type(8))) short bf16x8;
typedef __attribute__((ext_vector_type(4))) float f32x4;

// ---------------------------------------------------------------------------
// Projection GEMM: acc[m,n] = sum_k X[m,k] * W[n,k] + bias[n], output bf16.
// transpose_out==0: out[b,h,s,hd]  (q, k)
// transpose_out==1: out[b,h,hd,s]  (vT — so PV MFMA B-fragments are contiguous)
// ---------------------------------------------------------------------------
__global__ __launch_bounds__(256) void gemm_proj(
    const float* __restrict__ X, const float* __restrict__ W,
    const float* __restrict__ bias, __hip_bfloat16* __restrict__ out,
    int transpose_out) {
  __shared__ float As[64][33];
  __shared__ float Bs[64][33];
  const int tid = threadIdx.x;
  const int tx = tid & 15, ty = tid >> 4;
  const int n0 = blockIdx.x * 64;   // == h*64 (one head per n-tile)
  const int m0 = blockIdx.y * 64;
  float acc[4][4] = {};

  for (int k0 = 0; k0 < D; k0 += 32) {
#pragma unroll
    for (int i = 0; i < 8; ++i) {
      int l = tid + i * 256;
      int r = l >> 5, kk = l & 31;
      As[r][kk] = X[(size_t)(m0 + r) * D + (k0 + kk)];
      Bs[r][kk] = W[(size_t)(n0 + r) * D + (k0 + kk)];
    }
    __syncthreads();
#pragma unroll
    for (int kk = 0; kk < 32; ++kk) {
      float a[4], b[4];
#pragma unroll
      for (int i = 0; i < 4; ++i) a[i] = As[ty * 4 + i][kk];
#pragma unroll
      for (int j = 0; j < 4; ++j) b[j] = Bs[tx * 4 + j][kk];
#pragma unroll
      for (int i = 0; i < 4; ++i)
#pragma unroll
        for (int j = 0; j < 4; ++j) acc[i][j] += a[i] * b[j];
    }
    __syncthreads();
  }

  const int h = blockIdx.x;
#pragma unroll
  for (int i = 0; i < 4; ++i) {
    int m = m0 + ty * 4 + i;
    int b = m >> 11, s = m & 2047;
    __hip_bfloat16* obh = out + (size_t)b * STRIDE_B + (size_t)h * STRIDE_BH;
#pragma unroll
    for (int j = 0; j < 4; ++j) {
      int hd = tx * 4 + j;
      float v = acc[i][j] + bias[n0 + hd];
      if (transpose_out)
        obh[(size_t)hd * S + s] = __float2bfloat16(v);
      else
        obh[(size_t)s * HD + hd] = __float2bfloat16(v);
    }
  }
}

// ---------------------------------------------------------------------------
// Fused attention: per block = (bh, 64-query tile). 256 thr = 4 waves,
// each wave owns 16 query rows. Two passes over the 32 key-tiles:
//   A: S = qk^T (MFMA), l += rowsum(mask ? 0 : exp(s/8))        (no stores)
//   B: recompute S, p = e/l, write dist once, P->LDS->A-frag, O += P.V (MFMA)
// No max-subtraction: unmasked scores are O(1); masked exp underflows to 0,
// identical to the reference after normalization.
// ---------------------------------------------------------------------------
__global__ __launch_bounds__(256) void attn_fused(
    const __hip_bfloat16* __restrict__ q, const __hip_bfloat16* __restrict__ k,
    const __hip_bfloat16* __restrict__ vT, const int* __restrict__ mask,
    float* __restrict__ dist, float* __restrict__ attn) {
  __shared__ __hip_bfloat16 ps[4][16][72];   // per-wave P strip, stride 72 keeps
                                             // ds_read_b128 16B-aligned, 2-way banks

  const int tid = threadIdx.x;
  const int wave = tid >> 6;
  const int lane = tid & 63;
  const int l15 = lane & 15;
  const int quad = lane >> 4;
  const int qt = blockIdx.x >> 5;            // consecutive blocks share the mask
  const int bh = blockIdx.x & 31;            // strip (8 heads per batch) -> L2 reuse
  const int b = bh >> 3;
  const int row0 = qt * 64 + wave * 16;      // this wave's 16 query rows

  const __hip_bfloat16* qb  = q  + (size_t)bh * STRIDE_BH;
  const __hip_bfloat16* kb  = k  + (size_t)bh * STRIDE_BH;
  const __hip_bfloat16* vtb = vT + (size_t)bh * STRIDE_BH;   // [HD][S]
  const int* mb = mask + (size_t)b * S * S;
  float* distb = dist + (size_t)bh * S * S;
  float* attnb = attn + (size_t)bh * STRIDE_BH;

  // Q fragments (A-operand: m=l15, k=quad*8+j), held for both passes
  const bf16x8 qf0 = *(const bf16x8*)(qb + (size_t)(row0 + l15) * HD + quad * 8);
  const bf16x8 qf1 = *(const bf16x8*)(qb + (size_t)(row0 + l15) * HD + 32 + quad * 8);

  float lpart[4] = {0.f, 0.f, 0.f, 0.f};

  // ---- pass A: row sums ----
  for (int kt = 0; kt < 32; ++kt) {
    const int col0 = kt * 64;
#pragma unroll
    for (int ct = 0; ct < 4; ++ct) {
      const int col = col0 + ct * 16 + l15;
      const bf16x8 kf0 = *(const bf16x8*)(kb + (size_t)col * HD + quad * 8);
      const bf16x8 kf1 = *(const bf16x8*)(kb + (size_t)col * HD + 32 + quad * 8);
      f32x4 s = {0.f, 0.f, 0.f, 0.f};
      s = __builtin_amdgcn_mfma_f32_16x16x32_bf16(qf0, kf0, s, 0, 0, 0);
      s = __builtin_amdgcn_mfma_f32_16x16x32_bf16(qf1, kf1, s, 0, 0, 0);
#pragma unroll
      for (int r = 0; r < 4; ++r) {
        int row = row0 + quad * 4 + r;
        int msk = mb[(size_t)row * S + col];
        float e = msk ? 0.f : __expf(s[r] * 0.125f);
        lpart[r] += e;
      }
    }
  }
  // reduce across the 16 lanes of each quad group (they share the same 4 rows)
#pragma unroll
  for (int r = 0; r < 4; ++r) {
    float v = lpart[r];
    v += __shfl_xor(v, 1, 64);
    v += __shfl_xor(v, 2, 64);
    v += __shfl_xor(v, 4, 64);
    v += __shfl_xor(v, 8, 64);
    lpart[r] = 1.0f / v;                     // inv row sum
  }

  // ---- pass B: dist write + O = P.V ----
  f32x4 oacc[4] = {{0.f, 0.f, 0.f, 0.f}, {0.f, 0.f, 0.f, 0.f},
                   {0.f, 0.f, 0.f, 0.f}, {0.f, 0.f, 0.f, 0.f}};
  for (int kt = 0; kt < 32; ++kt) {
    const int col0 = kt * 64;
#pragma unroll
    for (int ct = 0; ct < 4; ++ct) {
      const int col = col0 + ct * 16 + l15;
      const bf16x8 kf0 = *(const bf16x8*)(kb + (size_t)col * HD + quad * 8);
      const bf16x8 kf1 = *(const bf16x8*)(kb + (size_t)col * HD + 32 + quad * 8);
      f32x4 s = {0.f, 0.f, 0.f, 0.f};
      s = __builtin_amdgcn_mfma_f32_16x16x32_bf16(qf0, kf0, s, 0, 0, 0);
      s = __builtin_amdgcn_mfma_f32_16x16x32_bf16(qf1, kf1, s, 0, 0, 0);
#pragma unroll
      for (int r = 0; r < 4; ++r) {
        int row = row0 + quad * 4 + r;
        int msk = mb[(size_t)row * S + col];
        float e = msk ? 0.f : __expf(s[r] * 0.125f);
        float p = e * lpart[r];
        distb[(size_t)row * S + col] = p;
        ps[wave][quad * 4 + r][ct * 16 + l15] = __float2bfloat16(p);
      }
    }
    // P strip (16x64) is wave-private: no __syncthreads needed, the compiler's
    // lgkmcnt tracking covers the same-wave LDS RAW.
    const bf16x8 pa0 = *(const bf16x8*)&ps[wave][l15][quad * 8];
    const bf16x8 pa1 = *(const bf16x8*)&ps[wave][l15][32 + quad * 8];
#pragma unroll
    for (int ct = 0; ct < 4; ++ct) {
      const __hip_bfloat16* vrow = vtb + (size_t)(ct * 16 + l15) * S + col0;
      const bf16x8 vf0 = *(const bf16x8*)(vrow + quad * 8);
      const bf16x8 vf1 = *(const bf16x8*)(vrow + 32 + quad * 8);
      oacc[ct] = __builtin_amdgcn_mfma_f32_16x16x32_bf16(pa0, vf0, oacc[ct], 0, 0, 0);
      oacc[ct] = __builtin_amdgcn_mfma_f32_16x16x32_bf16(pa1, vf1, oacc[ct], 0, 0, 0);
    }
  }

  // write O (fp32 [b,h,s,hd])
#pragma unroll
  for (int ct = 0; ct < 4; ++ct)
#pragma unroll
    for (int r = 0; r < 4; ++r) {
      int row = row0 + quad * 4 + r;
      attnb[(size_t)row * HD + ct * 16 + l15] = oacc[ct][r];
    }
}

// ---------------------------------------------------------------------------
// Output GEMM: x[m,n] = sum_k attn_flat[m,k] * Wo[n,k] + bo[n]
// ---------------------------------------------------------------------------
__global__ __launch_bounds__(256) void gemm_out(
    const float* __restrict__ attn, const float* __restrict__ W,
    const float* __restrict__ bias, float* __restrict__ out) {
  __shared__ float As[64][33];
  __shared__ float Bs[64][33];
  const int tid = threadIdx.x;
  const int tx = tid & 15, ty = tid >> 4;
  const int n0 = blockIdx.x * 64;
  const int m0 = blockIdx.y * 64;
  float acc[4][4] = {};

  for (int k0 = 0; k0 < D; k0 += 32) {
#pragma unroll
    for (int i = 0; i < 8; ++i) {
      int l = tid + i * 256;
      int r = l >> 5, kk = l & 31;
      int m = m0 + r, k = k0 + kk;
      int b = m >> 11, s = m & 2047, h = k >> 6, hd = k & 63;
      As[r][kk] = attn[(size_t)b * STRIDE_B + (size_t)h * STRIDE_BH + (size_t)s * HD + hd];
      Bs[r][kk] = W[(size_t)(n0 + r) * D + k];
    }
    __syncthreads();
#pragma unroll
    for (int kk = 0; kk < 32; ++kk) {
      float a[4], b[4];
#pragma unroll
      for (int i = 0; i < 4; ++i) a[i] = As[ty * 4 + i][kk];
#pragma unroll
      for (int j = 0; j < 4; ++j) b[j] = Bs[tx * 4 + j][kk];
#pragma unroll
      for (int i = 0; i < 4; ++i)
#pragma unroll
        for (int j = 0; j < 4; ++j) acc[i][j] += a[i] * b[j];
    }
    __syncthreads();
  }

#pragma unroll
  for (int i = 0; i < 4; ++i) {
    int m = m0 + ty * 4 + i;
#pragma unroll
    for (int j = 0; j < 4; ++j) {
      int n = n0 + tx * 4 + j;
      out[(size_t)m * D + n] = acc[i][j] + bias[n];
    }
  }
}

// ---------------------------------------------------------------------------
extern "C" void kernel_launch(void* const* d_in, const int* in_sizes, int n_in,
                              void* d_out, int out_size, void* d_ws, size_t ws_size,
                              hipStream_t stream) {
  const float* Q    = (const float*)d_in[0];
  const float* K    = (const float*)d_in[1];
  const float* V    = (const float*)d_in[2];
  const int*   mask = (const int*)d_in[3];
  const float* Wq   = (const float*)d_in[4];
  const float* bq   = (const float*)d_in[5];
  const float* Wk   = (const float*)d_in[6];
  const float* bk   = (const float*)d_in[7];
  const float* Wv   = (const float*)d_in[8];
  const float* bv   = (const float*)d_in[9];
  const float* Wo   = (const float*)d_in[10];
  const float* bo   = (const float*)d_in[11];

  float* x_out = (float*)d_out;              // [B,S,D]
  float* dist  = x_out + (size_t)X_SIZE;     // [B,H,S,S]

  __hip_bfloat16* qb  = (__hip_bfloat16*)d_ws;     // [B,H,S,HD]  bf16
  __hip_bfloat16* kbf = qb + (size_t)X_SIZE;       // [B,H,S,HD]  bf16
  __hip_bfloat16* vtb = kbf + (size_t)X_SIZE;      // [B,H,HD,S]  bf16
  float* attn = (float*)(vtb + (size_t)X_SIZE);    // [B,H,S,HD]  fp32

  dim3 blk(256);
  dim3 gproj(D / 64, M_TOT / 64);            // (8, 128)

  gemm_proj<<<gproj, blk, 0, stream>>>(Q, Wq, bq, qb, 0);
  gemm_proj<<<gproj, blk, 0, stream>>>(K, Wk, bk, kbf, 0);
  gemm_proj<<<gproj, blk, 0, stream>>>(V, Wv, bv, vtb, 1);
  attn_fused<<<dim3(B * H * S / 64), blk, 0, stream>>>(qb, kbf, vtb, mask, dist, attn);
  gemm_out<<<gproj, blk, 0, stream>>>(attn, Wo, bo, x_out);
}